// Round 1
// 158.606 us; speedup vs baseline: 1.0174x; 1.0174x over previous
//
#include <hip/hip_runtime.h>

typedef __attribute__((ext_vector_type(4))) unsigned int u32x4;
typedef __attribute__((ext_vector_type(4))) int i32x4;

union I16 { u32x4 u; i32x4 i; };

#define SA_INV   (127.0f / 12.0f)           // a = -2z, |a| <= 12 (z tail ~5.2)
#define SB_INV   (127.0f * 8192.0f)         // b in [-1/8192, 1/8192]
#define INV_SASB ((127.0 * 127.0 * 8192.0) / 12.0)   // 1/(sa*sb) ~ 1.101e7
#define WI       4500                        // refine window in int units (~4e-4)
#define FINF     3.4e38f

__device__ __forceinline__ int q8(float x, float s) {
    int q = (int)__builtin_rintf(x * s);
    return q < -127 ? -127 : (q > 127 ? 127 : q);
}

// async global->LDS, 16B per lane. LDS dest must be wave-uniform base; HW
// writes base + lane*16. Global src is per-lane.
__device__ __forceinline__ void glds16(const u32x4* g, u32x4* l) {
    __builtin_amdgcn_global_load_lds(
        (const __attribute__((address_space(1))) unsigned int*)g,
        (__attribute__((address_space(3))) unsigned int*)l, 16, 0, 0);
}

// ---------------------------------------------------------------------------
// prep_all: blocks 0..511 process the codebook (i8 B fragments in linear tile
// order, c2, ibt); blocks 512..1023 process z (i8 A fragments scaled by -2,
// zt row-major, z2f). UNCHANGED from the 161.4 us kernel.
// ---------------------------------------------------------------------------
__global__ __launch_bounds__(256)
void prep_all(const float* __restrict__ z, const float* __restrict__ cb,
              u32x4* __restrict__ ahi, float* __restrict__ zt,
              float* __restrict__ z2f, float* __restrict__ c2,
              unsigned int* __restrict__ ibt, u32x4* __restrict__ bstr) {
    __shared__ double pzbuf[32 * 9];              // doubles / pc floats
    __shared__ float tile[32 * 257];
    int tid = threadIdx.x;
    if (blockIdx.x < 512) {
        // ---- codebook path: one 16-code tile per block ----
        float* t16 = tile;                        // [16][257]
        float* pc = (float*)pzbuf;                // [16][17]
        int ct = blockIdx.x;
        int cl = tid >> 4, dseg = tid & 15;
        const float* src = cb + (size_t)(ct * 16 + cl) * 256 + dseg * 16;
        float s = 0.f;
#pragma unroll
        for (int i = 0; i < 16; ++i) { float v = src[i]; t16[cl * 257 + dseg * 16 + i] = v; s += v * v; }
        pc[cl * 17 + dseg] = s;
        __syncthreads();
        if (tid < 16) {
            float t = 0.f;
#pragma unroll
            for (int i = 0; i < 16; ++i) t += pc[tid * 17 + i];
            int code = ct * 16 + tid;
            c2[code] = t;
            int ib = (int)__builtin_rintf(t * (float)INV_SASB);
            ibt[code] = (((unsigned int)(ib + 262144)) << 6) | (unsigned int)((code >> 4) & 31);
        }
        int l = tid & 63, j = tid >> 6;
        int code_l = l & 15, k0 = j * 64 + ((l >> 4) << 4);
        u32x4 v;
#pragma unroll
        for (int d = 0; d < 4; ++d) {
            unsigned int wv = 0;
#pragma unroll
            for (int bb = 0; bb < 4; ++bb) {
                int q = q8(t16[code_l * 257 + k0 + d * 4 + bb], SB_INV);
                wv |= ((unsigned int)(q & 255)) << (8 * bb);
            }
            v[d] = wv;
        }
        bstr[(size_t)(ct * 4 + j) * 64 + l] = v;
    } else {
        // ---- z path: one (b,h) pair per block ----
        int bh = blockIdx.x - 512;                // 0..511
        int b = bh >> 5, h = bh & 31;
        for (int e = tid; e < 8192; e += 256) {
            int d = e >> 5, w = e & 31;
            tile[w * 257 + d] = z[((size_t)(b * 256 + d) * 32 + h) * 32 + w];
        }
        __syncthreads();
        for (int e = tid; e < 8192; e += 256) {
            int w = e >> 8, d = e & 255;
            zt[(size_t)(bh * 32 + w) * 256 + d] = tile[w * 257 + d];
        }
        {
            int w = tid >> 3, seg = tid & 7;
            double s = 0.0;
#pragma unroll
            for (int d = 0; d < 32; ++d) { double v = (double)tile[w * 257 + seg * 32 + d]; s += v * v; }
            pzbuf[w * 9 + seg] = s;
        }
        __syncthreads();
        if (tid < 32) {
            double s = 0.0;
#pragma unroll
            for (int seg = 0; seg < 8; ++seg) s += pzbuf[tid * 9 + seg];
            z2f[bh * 32 + tid] = (float)s;
        }
        for (int o = tid; o < 512; o += 256) {    // 2 row-tiles x 4 j x 64 lanes
            int l = o & 63, j = (o >> 6) & 3, tt = o >> 8;
            int wp = tt * 16 + (l & 15);
            int k0 = j * 64 + ((l >> 4) << 4);
            u32x4 v;
#pragma unroll
            for (int d = 0; d < 4; ++d) {
                unsigned int wv = 0;
#pragma unroll
                for (int bb = 0; bb < 4; ++bb) {
                    int q = q8(-2.0f * tile[wp * 257 + k0 + d * 4 + bb], SA_INV);
                    wv |= ((unsigned int)(q & 255)) << (8 * bb);
                }
                v[d] = wv;
            }
            ahi[(size_t)bh * 512 + o] = v;
        }
    }
}

// ---------------------------------------------------------------------------
// vq_main R9: block-cooperative LDS staging (T3-lite 2-phase template).
//   - Per phase: stage the NEXT 2 code-tiles (8 KB) into lbuf[cur^1] via
//     global_load_lds width=16 (linear dest == fragment read order, no
//     swizzle), compute the 2 current tiles from lbuf[cur], __syncthreads
//     (drains vmcnt+lgkmcnt), swap. 16 phases x 2 tiles = 32 tiles.
//   - ibt stripe slice staged once into LDS (2 KB).
//   - Integer math (tilework asm, fragment layouts, top-3 tail) is
//     BIT-IDENTICAL to the verified R7 kernel; only the data movement and
//     register footprint changed (drops the 32-VGPR per-wave B double-buffer,
//     cuts in-loop VMEM instructions 4x across the block's 4 waves).
// ---------------------------------------------------------------------------
__global__ __launch_bounds__(256)
void vq_main(const u32x4* __restrict__ ahi4, const u32x4* __restrict__ bstr,
             const unsigned int* __restrict__ ibt,
             unsigned int* __restrict__ cd, int* __restrict__ ci) {
    __shared__ u32x4 lbuf[2][2][256];             // 16 KB: [buf][tile][elem]
    __shared__ unsigned int libt[512];            // 2 KB: ibt stripe slice
    int tid = threadIdx.x;
    int wid = tid >> 6, lane = tid & 63;
    int stripe = blockIdx.x & 15;
    int rg = blockIdx.x >> 4;                     // 0..127
    int colc = lane & 15;
    int rt0 = rg * 8 + wid * 2;                   // wave's 2 row-tiles (32 rows)

    for (int e = tid; e < 512; e += 256) libt[e] = ibt[stripe * 512 + e];

    I16 ah[2][4];
#pragma unroll
    for (int rt = 0; rt < 2; ++rt)
#pragma unroll
        for (int j = 0; j < 4; ++j)
            ah[rt][j].u = ahi4[((size_t)(rt0 + rt) * 4 + j) * 64 + lane];

    unsigned int m1[8], m2[8];
#pragma unroll
    for (int s = 0; s < 8; ++s) { m1[s] = 0xFFFFFFFFu; m2[s] = 0xFFFFFFFFu; }

    // element tid of tile 0 in this stripe's slice (8192 u32x4 = 128 KB)
    const u32x4* gsrc = bstr + (size_t)stripe * 8192 + tid;
    int ldsbase = wid << 6;                       // wave-uniform element base

    // prologue: stage tiles 0,1 into buf 0 (also covers libt via barrier)
    glds16(gsrc,       &lbuf[0][0][ldsbase]);
    glds16(gsrc + 256, &lbuf[0][1][ldsbase]);
    __syncthreads();                              // drains vmcnt(0)+lgkmcnt(0)

    i32x4 zc = (i32x4){0, 0, 0, 0};

    auto tilework = [&](const I16 (&bf)[4], unsigned int ibv) {
        i32x4 acc0, acc1;
        acc0 = __builtin_amdgcn_mfma_i32_16x16x64_i8(ah[0][0].i, bf[0].i, zc, 0, 0, 0);
        acc1 = __builtin_amdgcn_mfma_i32_16x16x64_i8(ah[1][0].i, bf[0].i, zc, 0, 0, 0);
#pragma unroll
        for (int j = 1; j < 4; ++j) {
            acc0 = __builtin_amdgcn_mfma_i32_16x16x64_i8(ah[0][j].i, bf[j].i, acc0, 0, 0, 0);
            acc1 = __builtin_amdgcn_mfma_i32_16x16x64_i8(ah[1][j].i, bf[j].i, acc1, 0, 0, 0);
        }
#pragma unroll
        for (int s = 0; s < 8; ++s) {
            unsigned int av = (unsigned int)((s < 4) ? acc0[s & 3] : acc1[s & 3]);
            unsigned int key, tmp;
            asm("v_lshl_add_u32 %0, %4, 6, %5\n\t"
                "v_max_u32 %1, %0, %2\n\t"
                "v_min_u32 %3, %3, %1\n\t"
                "v_min_u32 %2, %2, %0"
                : "=&v"(key), "=&v"(tmp), "+v"(m1[s]), "+v"(m2[s])
                : "v"(av), "v"(ibv));
        }
    };

    int cur = 0;
    for (int p = 0; p < 16; ++p) {
        if (p < 15) {                             // issue next phase's stage
            const u32x4* gs = gsrc + (size_t)(p + 1) * 512;
            glds16(gs,       &lbuf[cur ^ 1][0][ldsbase]);
            glds16(gs + 256, &lbuf[cur ^ 1][1][ldsbase]);
        }
#pragma unroll
        for (int tt = 0; tt < 2; ++tt) {
            I16 bf[4];
#pragma unroll
            for (int j = 0; j < 4; ++j) bf[j].u = lbuf[cur][tt][j * 64 + lane];
            unsigned int ibv = libt[(p * 2 + tt) * 16 + colc];
            tilework(bf, ibv);
        }
        __syncthreads();                          // stage done + reads drained
        cur ^= 1;
    }

    // tail: per row-slot, top-3 of the 16 (m1,m2) across the 16 lanes sharing
    // the row (equal lane>>4; xor masks 1,2,4,8 stay in-group). UNCHANGED.
#pragma unroll
    for (int s = 0; s < 8; ++s) {
        int rt = s >> 2, r = s & 3;
        int row = (rt0 + rt) * 16 + (lane >> 4) * 4 + r;
        unsigned int v0 = m1[s], v1 = m2[s];
        int c0 = stripe * 512 + (int)(v0 & 63) * 16 + colc;
        int c1 = stripe * 512 + (int)(v1 & 63) * 16 + colc;
        int obase = (row * 16 + stripe) * 3;
#pragma unroll
        for (int k = 0; k < 3; ++k) {
            unsigned int bv; int bi;
            if (v1 < v0) { bv = v1; bi = c1; } else { bv = v0; bi = c0; }
#pragma unroll
            for (int mm = 1; mm < 16; mm <<= 1) {
                unsigned int ov = __shfl_xor(bv, mm, 64);
                int oi = __shfl_xor(bi, mm, 64);
                if (ov < bv || (ov == bv && oi < bi)) { bv = ov; bi = oi; }
            }
            if (colc == k) { cd[obase + k] = bv; ci[obase + k] = bi; }
            if (bi == c0) v0 = 0xFFFFFFFFu;
            if (bi == c1) v1 = 0xFFFFFFFFu;
        }
    }
}

// ---------------------------------------------------------------------------
// refine: one wave per row, 48 candidates. Exact np f32 semantics (R2-R7
// verified): f64 dot rounded once, d1 = fl32(z2 - 2*Mf), d2 = fl32(d1 + c2),
// argmin with first-index ties. Window filter on int keys. UNCHANGED.
// ---------------------------------------------------------------------------
__global__ __launch_bounds__(256)
void refine(const float* __restrict__ zt, const float* __restrict__ z2f,
            const float* __restrict__ cb, const float* __restrict__ c2,
            const unsigned int* __restrict__ cd, const int* __restrict__ ci,
            float* __restrict__ out, int* __restrict__ idxi) {
    int wid = threadIdx.x >> 6, lane = threadIdx.x & 63;
    int n = blockIdx.x * 4 + wid;
    float zq[4];
#pragma unroll
    for (int q = 0; q < 4; ++q) zq[q] = zt[(size_t)n * 256 + q * 64 + lane];
    float z2v = z2f[n];

    unsigned int kd = 0xFFFFFFFFu; int civ = 0;
    if (lane < 48) { kd = cd[n * 48 + lane]; civ = ci[n * 48 + lane]; }
    unsigned int rm = kd;
#pragma unroll
    for (int m = 32; m >= 1; m >>= 1) {
        unsigned int o = __shfl_xor(rm, m, 64);
        rm = o < rm ? o : rm;
    }
    bool active = (lane < 48) && ((kd >> 6) <= (rm >> 6) + WI);
    unsigned long long mask = __ballot(active);
    float bestd = FINF; int besti = 0x7fffffff;
    while (mask) {
        int k = __ffsll(mask) - 1;
        mask &= mask - 1;
        int cidx = __shfl(civ, k, 64);
        const float* crow = cb + (size_t)cidx * 256;
        double dot = 0.0;
#pragma unroll
        for (int q = 0; q < 4; ++q)
            dot += (double)zq[q] * (double)crow[q * 64 + lane];
#pragma unroll
        for (int m = 32; m >= 1; m >>= 1) dot += __shfl_xor(dot, m, 64);
        float Mf = (float)dot;
        float d1 = z2v - 2.0f * Mf;
        float d2 = d1 + c2[cidx];
        if (d2 < bestd || (d2 == bestd && cidx < besti)) { bestd = d2; besti = cidx; }
    }
    if (lane == 0) {
        idxi[n] = besti;
        out[4194304 + n] = (float)besti;
    }
}

// ---------------------------------------------------------------------------
// gather: z_q[b,d,h,w] = codebook[idx[b,h,w]][d], LDS transpose per (b,h)
// ---------------------------------------------------------------------------
__global__ void gather_out(const float* __restrict__ cb,
                           const int* __restrict__ idxi,
                           float* __restrict__ out) {
    __shared__ float tile[32][257];
    __shared__ int sidx[32];
    int b = blockIdx.x >> 5, h = blockIdx.x & 31;
    int tid = threadIdx.x;
    if (tid < 32) sidx[tid] = idxi[(b * 32 + h) * 32 + tid];
    __syncthreads();
    for (int e = tid; e < 8192; e += 256) {
        int w = e >> 8, d = e & 255;
        tile[w][d] = cb[(size_t)sidx[w] * 256 + d];
    }
    __syncthreads();
    for (int e = tid; e < 8192; e += 256) {
        int d = e >> 5, w = e & 31;
        out[(((size_t)b * 256 + d) * 32 + h) * 32 + w] = tile[w][d];
    }
}

// ---------------------------------------------------------------------------
extern "C" void kernel_launch(void* const* d_in, const int* in_sizes, int n_in,
                              void* d_out, int out_size, void* d_ws, size_t ws_size,
                              hipStream_t stream) {
    const float* z  = (const float*)d_in[0];      // [16,256,32,32]
    const float* cb = (const float*)d_in[1];      // [8192,256]
    float* out = (float*)d_out;                   // z_q (4194304) + idx (16384)
    char* w = (char*)d_ws;
    // ws layout (bytes):
    //   ahi   0 .. 4,194,304 (4MB)  [idxi overlaid after vq_main]
    //   bstr  4,194,304 .. 6,291,456 (2MB)
    //   zt    6,291,456 .. 23,068,672 (16MB)
    //   c2 23,068,672 (+32K) | ibt 23,101,440 (+32K) | z2f 23,134,208 (+64K)
    //   cd 23,199,744 (+3M) | ci 26,345,472 (+3M) -> end 29,491,200
    u32x4* ahi  = (u32x4*)(w);
    u32x4* bstr = (u32x4*)(w + 4194304);
    float* zt   = (float*)(w + 6291456);
    float* c2   = (float*)(w + 23068672);
    unsigned int* ibt = (unsigned int*)(w + 23101440);
    float* z2f  = (float*)(w + 23134208);
    unsigned int* cd = (unsigned int*)(w + 23199744);
    int*   ci   = (int*)(w + 26345472);
    int*   idxi = (int*)(w);                      // overlays dead ahi region

    prep_all<<<1024, 256, 0, stream>>>(z, cb, ahi, zt, z2f, c2, ibt, bstr);
    vq_main<<<2048, 256, 0, stream>>>(ahi, bstr, ibt, cd, ci);
    refine<<<4096, 256, 0, stream>>>(zt, z2f, cb, c2, cd, ci, out, idxi);
    gather_out<<<512, 256, 0, stream>>>(cb, idxi, out);
}